// Round 1
// baseline (78.566 us; speedup 1.0000x reference)
//
#include <hip/hip_runtime.h>

// Path signature depth-3, path (N=32, L=128, C=48) fp32 — fused single kernel.
//
// Math (R5/R9-validated, absmax 0.25):
//   v_t = p[t+1]-p[t], P_t[i] = p[t][i]-p[0][i],
//   G_t = P_t + v_t/2,  R_t = P_t/2 + v_t/6
//   S1 = p[127]-p[0];  S2[i,j] = sum_t G_t[i] v_t[j]   (register prefix a2)
//   S3[i,j,k] = sum_t (a2prefix + R_t[i] v_t[j]) v_t[k]
//   t-split x4 (32/32/32/31), Pi seeded globally per segment; exact fixup
//   S3 = sum_q [S3loc_q + a2pre_q (x) W_q], W_q = p[seg_end]-p[seg_start].
//
// R12: pipe-model post-mortem of R11 (pk-fma neutral): main loop is
// LDS-pipe-bound, not VALU-bound. 4x ds_read_b128 + ds_read_b32 ~= 54
// LDS cyc/wave-iter -> 9.7 us/CU of the ~12.7 us kernel (VALUBusy 57%
// back-solve matches VALU ~7.5 us scalar). This round: source the
// k-chunk from GLOBAL (L1/L2-hot p rows, v_k formed by register diff,
// 2-deep prefetch) -> LDS 54->30 cyc/iter; k moves to the idle VMEM
// pipe (2x dwordx4, 6-distinct-addr coalesced). Also packs {b_, a2}
// update into one pk-fma. Bit-identical arithmetic. Predicted kernel
// ~8 us, total ~70-71 us.

#define N_BATCH 32
#define LPATH   128
#define T_STEPS 127
#define C       48
#define C2      2304
#define C3      110592
#define OUT_PER_N (C + C2 + C3)      // 112944
#define PATH_PER_N (LPATH * C)       // 6144
#define GROUPS 27                    // 1728 (i,jg,kc) units / 64 lanes
#define RSLOT 36                     // per-q slots/round: 4jj*8k + 4 a2
#define LDS_FLOATS 6912              // max(v: 6096, reduce: 3*36*64=6912)

typedef float f32x2 __attribute__((ext_vector_type(2)));

__global__ __launch_bounds__(256, 2) void sig_fused(const float* __restrict__ path,
                                                    float* __restrict__ out) {
    __shared__ float lds[LDS_FLOATS];

    int bid = blockIdx.x;
    int n = bid / GROUPS;
    int g = bid - n * GROUPS;
    int tid = threadIdx.x;
    int q = tid >> 6;                // t-segment 0..3
    int lane = tid & 63;

    const float* __restrict__ pb = path + n * PATH_PER_N;

    // ---- stage v = diff(p) into LDS (coalesced float4) ----
    {
        const float4* p4 = (const float4*)pb;
        float4* v4 = (float4*)lds;
        #pragma unroll
        for (int c = 0; c < 6; ++c) {
            int idx = tid + 256 * c;
            if (idx < (T_STEPS * C) / 4) {            // 1524
                float4 a = p4[idx];
                float4 b = p4[idx + C / 4];
                v4[idx] = make_float4(b.x - a.x, b.y - a.y, b.z - a.z, b.w - a.w);
            }
        }
    }
    // S1 (once per batch), overlapped with staging
    if (g == 0 && tid < C)
        out[(long)n * OUT_PER_N + tid] = pb[(LPATH - 1) * C + tid] - pb[tid];
    __syncthreads();

    // unit U -> (i, jg, kc): U = i*36 + jg*6 + kc ; j = jg*8+[0,8), k = kc*8+[0,8)
    int U = g * 64 + lane;
    int i = U / 36;
    int rr = U - i * 36;
    int jg = rr / 6;
    int kc = rr - jg * 6;

    int T0 = q * 32;
    int T1 = (q == 3) ? T_STEPS : (T0 + 32);

    float Pi = pb[T0 * C + i] - pb[i];   // exact global prefix at segment start
    float a2[8];
    f32x2 s3[8][4];                      // packed k-pairs: [jj][kpair]
    #pragma unroll
    for (int jj = 0; jj < 8; ++jj) {
        a2[jj] = 0.f;
        #pragma unroll
        for (int p = 0; p < 4; ++p) s3[jj][p] = (f32x2){0.f, 0.f};
    }

    // ---- global k-chunk pipeline (rows of p, 2-deep prefetch) ----
    // v_k(t) = p[t+1][k] - p[t][k], formed in registers. L1/L2-hot:
    // only 6 distinct 16B segments per wave-load -> fully coalesced.
    const float* gk = pb + kc * 8;
    f32x2 kP0, kP1, kP2, kP3;            // row t
    f32x2 kN0, kN1, kN2, kN3;            // row t+1
    f32x2 kF0, kF1, kF2, kF3;            // row t+2 (in flight)
    {
        float4 a0 = *(const float4*)(gk + T0 * C);
        float4 a1 = *(const float4*)(gk + T0 * C + 4);
        float4 b0 = *(const float4*)(gk + (T0 + 1) * C);
        float4 b1 = *(const float4*)(gk + (T0 + 1) * C + 4);
        float4 c0 = *(const float4*)(gk + (T0 + 2) * C);
        float4 c1 = *(const float4*)(gk + (T0 + 2) * C + 4);
        kP0 = (f32x2){a0.x, a0.y}; kP1 = (f32x2){a0.z, a0.w};
        kP2 = (f32x2){a1.x, a1.y}; kP3 = (f32x2){a1.z, a1.w};
        kN0 = (f32x2){b0.x, b0.y}; kN1 = (f32x2){b0.z, b0.w};
        kN2 = (f32x2){b1.x, b1.y}; kN3 = (f32x2){b1.z, b1.w};
        kF0 = (f32x2){c0.x, c0.y}; kF1 = (f32x2){c0.z, c0.w};
        kF2 = (f32x2){c1.x, c1.y}; kF3 = (f32x2){c1.z, c1.w};
    }

    // ---- LDS j/i pipeline (1-deep prefetch, as before) ----
    float4 cvj0, cvj1;
    float  cvi;
    {
        const float* base = lds + T0 * C;
        cvj0 = *(const float4*)(base + jg * 8);
        cvj1 = *(const float4*)(base + jg * 8 + 4);
        cvi  = base[i];
    }

#define SIGCOMPUTE() do {                                               \
        float G = Pi + 0.5f * cvi;                                      \
        float R = 0.5f * Pi + (1.0f / 6.0f) * cvi;                      \
        Pi += cvi;                                                      \
        f32x2 RG = {R, G};                                              \
        f32x2 kk0 = kN0 - kP0;                                          \
        f32x2 kk1 = kN1 - kP1;                                          \
        f32x2 kk2 = kN2 - kP2;                                          \
        f32x2 kk3 = kN3 - kP3;                                          \
        float vja[8] = {cvj0.x, cvj0.y, cvj0.z, cvj0.w,                 \
                        cvj1.x, cvj1.y, cvj1.z, cvj1.w};                \
        _Pragma("unroll")                                               \
        for (int jj = 0; jj < 8; ++jj) {                                \
            f32x2 vjp = {vja[jj], vja[jj]};                             \
            f32x2 aap = {a2[jj], a2[jj]};                               \
            f32x2 t2 = __builtin_elementwise_fma(RG, vjp, aap);         \
            a2[jj] = t2.y;                                              \
            f32x2 bb = {t2.x, t2.x};                                    \
            s3[jj][0] = __builtin_elementwise_fma(bb, kk0, s3[jj][0]);  \
            s3[jj][1] = __builtin_elementwise_fma(bb, kk1, s3[jj][1]);  \
            s3[jj][2] = __builtin_elementwise_fma(bb, kk2, s3[jj][2]);  \
            s3[jj][3] = __builtin_elementwise_fma(bb, kk3, s3[jj][3]);  \
        }                                                               \
    } while (0)

    #pragma unroll 2
    for (int t = T0; t < T1 - 1; ++t) {
        // prefetch LDS j/i for t+1
        const float* nb = lds + (t + 1) * C;
        float4 nvj0 = *(const float4*)(nb + jg * 8);
        float4 nvj1 = *(const float4*)(nb + jg * 8 + 4);
        float  nvi  = nb[i];
        // prefetch global k row t+3 (clamped; only q==3 can hit the clamp)
        int tr = t + 3; if (tr > LPATH - 1) tr = LPATH - 1;
        float4 g0 = *(const float4*)(gk + tr * C);
        float4 g1 = *(const float4*)(gk + tr * C + 4);
        SIGCOMPUTE();
        // rotate pipelines (renamed away under unroll 2)
        kP0 = kN0; kP1 = kN1; kP2 = kN2; kP3 = kN3;
        kN0 = kF0; kN1 = kF1; kN2 = kF2; kN3 = kF3;
        kF0 = (f32x2){g0.x, g0.y}; kF1 = (f32x2){g0.z, g0.w};
        kF2 = (f32x2){g1.x, g1.y}; kF3 = (f32x2){g1.z, g1.w};
        cvj0 = nvj0; cvj1 = nvj1; cvi = nvi;
    }
    SIGCOMPUTE();                    // last t of this segment
#undef SIGCOMPUTE

    // ---- W vectors for the fixup (wave 3 only; L2-hot global reads) ----
    float4 W10, W11, W20, W21, W30, W31;
    if (q == 3) {
        float4 p32a = *(const float4*)(pb + 32 * C + kc * 8);
        float4 p32b = *(const float4*)(pb + 32 * C + kc * 8 + 4);
        float4 p64a = *(const float4*)(pb + 64 * C + kc * 8);
        float4 p64b = *(const float4*)(pb + 64 * C + kc * 8 + 4);
        float4 p96a = *(const float4*)(pb + 96 * C + kc * 8);
        float4 p96b = *(const float4*)(pb + 96 * C + kc * 8 + 4);
        float4 pEa  = *(const float4*)(pb + 127 * C + kc * 8);
        float4 pEb  = *(const float4*)(pb + 127 * C + kc * 8 + 4);
        W10 = make_float4(p64a.x - p32a.x, p64a.y - p32a.y, p64a.z - p32a.z, p64a.w - p32a.w);
        W11 = make_float4(p64b.x - p32b.x, p64b.y - p32b.y, p64b.z - p32b.z, p64b.w - p32b.w);
        W20 = make_float4(p96a.x - p64a.x, p96a.y - p64a.y, p96a.z - p64a.z, p96a.w - p64a.w);
        W21 = make_float4(p96b.x - p64b.x, p96b.y - p64b.y, p96b.z - p64b.z, p96b.w - p64b.w);
        W30 = make_float4(pEa.x - p96a.x, pEa.y - p96a.y, pEa.z - p96a.z, pEa.w - p96a.w);
        W31 = make_float4(pEb.x - p96b.x, pEb.y - p96b.y, pEb.z - p96b.z, pEb.w - p96b.w);
    }

    __syncthreads();                 // all waves done reading v

    // ---- 2 rounds: waves 0-2 deposit 4 jj's, wave 3 combines + stores ----
    long obase = (long)n * OUT_PER_N + C;
    #pragma unroll
    for (int r = 0; r < 2; ++r) {
        if (r) __syncthreads();      // protect previous round's reads
        if (q < 3) {
            float* dst = lds + (q * RSLOT) * 64 + lane;   // lane-major slots
            #pragma unroll
            for (int jjr = 0; jjr < 4; ++jjr) {
                int jj = r * 4 + jjr;
                dst[(jjr * 8 + 0) * 64] = s3[jj][0][0];
                dst[(jjr * 8 + 1) * 64] = s3[jj][0][1];
                dst[(jjr * 8 + 2) * 64] = s3[jj][1][0];
                dst[(jjr * 8 + 3) * 64] = s3[jj][1][1];
                dst[(jjr * 8 + 4) * 64] = s3[jj][2][0];
                dst[(jjr * 8 + 5) * 64] = s3[jj][2][1];
                dst[(jjr * 8 + 6) * 64] = s3[jj][3][0];
                dst[(jjr * 8 + 7) * 64] = s3[jj][3][1];
                dst[(32 + jjr) * 64]    = a2[jj];
            }
        }
        __syncthreads();
        if (q == 3) {
            #pragma unroll
            for (int jjr = 0; jjr < 4; ++jjr) {
                int jj = r * 4 + jjr;
                const float* s0 = lds + (0 * RSLOT) * 64 + lane;
                const float* s1 = lds + (1 * RSLOT) * 64 + lane;
                const float* s2 = lds + (2 * RSLOT) * 64 + lane;
                float a2q0 = s0[(32 + jjr) * 64];
                float a2q1 = s1[(32 + jjr) * 64];
                float a2q2 = s2[(32 + jjr) * 64];
                float pre1 = a2q0;
                float pre2 = a2q0 + a2q1;
                float pre3 = pre2 + a2q2;
                float acc[8];
                #pragma unroll
                for (int c = 0; c < 8; ++c) {
                    int sl = (jjr * 8 + c) * 64;
                    acc[c] = s0[sl] + s1[sl] + s2[sl];
                }
                acc[0] += s3[jj][0][0] + pre1 * W10.x + pre2 * W20.x + pre3 * W30.x;
                acc[1] += s3[jj][0][1] + pre1 * W10.y + pre2 * W20.y + pre3 * W30.y;
                acc[2] += s3[jj][1][0] + pre1 * W10.z + pre2 * W20.z + pre3 * W30.z;
                acc[3] += s3[jj][1][1] + pre1 * W10.w + pre2 * W20.w + pre3 * W30.w;
                acc[4] += s3[jj][2][0] + pre1 * W11.x + pre2 * W21.x + pre3 * W31.x;
                acc[5] += s3[jj][2][1] + pre1 * W11.y + pre2 * W21.y + pre3 * W31.y;
                acc[6] += s3[jj][3][0] + pre1 * W11.z + pre2 * W21.z + pre3 * W31.z;
                acc[7] += s3[jj][3][1] + pre1 * W11.w + pre2 * W21.w + pre3 * W31.w;

                float* dst = out + obase + C2 + (long)(i * C + jg * 8 + jj) * C + kc * 8;
                *(float4*)(dst)     = make_float4(acc[0], acc[1], acc[2], acc[3]);
                *(float4*)(dst + 4) = make_float4(acc[4], acc[5], acc[6], acc[7]);
                if (kc == 0)
                    out[obase + i * C + jg * 8 + jj] = pre3 + a2[jj];   // S2
            }
        }
    }
}

extern "C" void kernel_launch(void* const* d_in, const int* in_sizes, int n_in,
                              void* d_out, int out_size, void* d_ws, size_t ws_size,
                              hipStream_t stream) {
    const float* path = (const float*)d_in[0];
    float* out = (float*)d_out;
    (void)d_ws; (void)ws_size;

    sig_fused<<<N_BATCH * GROUPS, 256, 0, stream>>>(path, out);
}